// Round 4
// baseline (75.094 us; speedup 1.0000x reference)
//
#include <hip/hip_runtime.h>

// Conv4D (2,8,7,7,48,48) fp32, 3x3x3x3 pad 1, 8->8 ch — bf16 MFMA implicit GEMM.
// R15 = R14 + wf-fragments served from LDS (Wp2 staged once per block).
//   Model (R13 slope: +78 MB L2 traffic -> +2.1 us => ~37 GB/us = L2 peak):
//   conv is L2/VMEM-pipe-bound at ~6.5 us for 234 MB. wf loads are 78 MB of
//   that, re-reading a 27 KB array per wave. Stage Wp2 -> LDS per block;
//   wf becomes ds_read_b128 (DS pipe, lane-contiguous = conflict-free).
//   Blocks widened to 256 thr / 4 waves / 8 dtiles (882 = 98 img x 9) so the
//   27.6 KB LDS does not cap occupancy (3.45 blk/CU * 27.6 KB = 95 KB/CU;
//   13.8 waves/CU preserved; launch_bounds(256,4) caps VGPR at 128).
//   Staging 24 MB replaces 78 MB of wf VMEM traffic (-23% total, 234->180 MB).
//
// d_ws layout (re-poisoned each launch; fully rewritten by prep):
//   [0,       3920000)  xp: bf16 x as [b][uv 49][hh 50][ww 50][c 8], halo zeros
//   [3920000, 3960000)  zero slice (40 KB) backing invalid (u,v) slices
//   [3960000, 3987648)  Wp2: A-frags [aslot 27 = i0i1*3+i3][lane 64][j 8] bf16
//                       Wp2[as][lane][j] = W[o=m&7, i0i1, i2=q-d, i3, c=j],
//                       m=lane&15, q=lane>>4, d=m>>3; zero if q-d not in 0..2
//   [3987648, 3991176)  tbl: [img 98][k 9] i32 = uvbase | (i0i1 << 22)

typedef __attribute__((ext_vector_type(8))) short short8;
typedef __attribute__((ext_vector_type(4))) float f32x4;

#define CSTRIDE (49 * 2304)
#define ZS_OFF  3920000
#define WP_OFF  3960000
#define WT_OFF  3987648

__device__ __forceinline__ unsigned short f2bf(float f) {
    union { float f; unsigned u; } v; v.f = f;
    unsigned u = v.u;
    return (unsigned short)((u + 0x7FFF + ((u >> 16) & 1)) >> 16);  // RNE
}

// prep jobs (92862 threads total):
//   [0,      56448)  interior: 98 img x 48 rows x 12 quads; 8x float4 -> 4 recs
//   [56448,  78156)  halo zeros (19208) + zero slice (2500): 16 B stores
//   [78156,  91980)  Wp2: 27 aslots * 512 elems
//   [91980,  92862)  tbl: [img 98][k 9]
__global__ __launch_bounds__(256)
void prep(const float* __restrict__ x, const float* __restrict__ conv,
          unsigned short* __restrict__ ws16) {
    int g = blockIdx.x * 256 + threadIdx.x;
    if (g < 56448) {                          // interior, branch-free
        int img = g / 576;                    // 48 rows * 12 quads
        int r   = g - img * 576;
        int hh1 = r / 12;                     // 0..47  (xp row hh = hh1+1)
        int t   = r - hh1 * 12;               // quad 0..11
        int b   = img / 49;
        int uv  = img - b * 49;
        const float* xb = x + ((size_t)(b * 8) * 49 + uv) * 2304 + hh1 * 48 + t * 4;
        f32x4 vf[8];
#pragma unroll
        for (int c = 0; c < 8; ++c)
            vf[c] = *(const f32x4*)(xb + (size_t)c * CSTRIDE);
        // 8x4 register transpose -> 4 contiguous pixel records [c 8] bf16.
        size_t rec = (size_t)img * 2500 + (hh1 + 1) * 50 + (t * 4 + 1);
        unsigned short* wp = ws16 + rec * 8;
#pragma unroll
        for (int k = 0; k < 4; ++k) {
            unsigned short vals[8];
#pragma unroll
            for (int c = 0; c < 8; ++c) vals[c] = f2bf(vf[c][k]);
            *(short8*)(wp + k * 8) = *(const short8*)vals;
        }
        return;
    }
    g -= 56448;
    if (g < 21708) {                          // halo zeros + zero slice
        size_t rec;
        if (g < 19208) {
            int img = g / 196;
            int r   = g - img * 196;
            int hh, ww;
            if (r < 100) { hh = (r < 50) ? 0 : 49; ww = (r < 50) ? r : r - 50; }
            else         { int s = r - 100; hh = 1 + (s >> 1); ww = (s & 1) * 49; }
            rec = (size_t)img * 2500 + hh * 50 + ww;
        } else {
            rec = 245000 + (size_t)(g - 19208);   // zero slice
        }
        *(short8*)(ws16 + rec * 8) = (short8){0, 0, 0, 0, 0, 0, 0, 0};
        return;
    }
    g -= 21708;
    if (g < 13824) {                          // Wp2: 27 aslots * 512 elems
        int as   = g >> 9;
        int r    = g & 511;
        int lane = r >> 3, j = r & 7;
        int m = lane & 15, q = lane >> 4;
        int o = m & 7, d = m >> 3;
        int i0i1 = as / 3, i3 = as - 3 * i0i1;
        int i2 = q - d;
        unsigned short v = 0;
        if ((unsigned)i2 < 3u)
            v = f2bf(conv[o * 648 + ((i0i1 * 3 + i2) * 3 + i3) * 8 + j]);
        ws16[WP_OFF / 2 + g] = v;
        return;
    }
    g -= 13824;
    if (g < 882) {                            // tbl[img 98][k 9]
        int img = g / 9, k = g - img * 9;
        int b   = img / 49, uv = img - b * 49;
        int u   = uv / 7,   v  = uv - u * 7;
        int entry = ZS_OFF;                   // default: zero slice, i0i1=0
        int cnt = 0;
        for (int i01 = 0; i01 < 9; ++i01) {
            int i0 = i01 / 3, i1 = i01 - 3 * i0;
            int uu = u + i0 - 1, vv = v + i1 - 1;
            if (((unsigned)uu < 7u) && ((unsigned)vv < 7u)) {
                if (cnt == k)
                    entry = (((b * 7 + uu) * 7 + vv) * 40000) | (i01 << 22);
                ++cnt;
            }
        }
        ((int*)((char*)ws16 + WT_OFF))[g] = entry;
    }
}

// Main: 1D grid 882 blocks, 256 thr = 4 waves; wave = 2 dtiles (2 rows x 16
// cols each). Wp2 (27.6 KB) staged to LDS once per block; wf = ds_read_b128.
// Bijective chunked XCD remap: 882 = 8*110 + 2 (xcd 0,1 get 111).
__global__ __launch_bounds__(256, 4)
void conv4d_mfma(const unsigned short* __restrict__ ws16,
                 const float* __restrict__ bias,
                 float* __restrict__ out) {
    __shared__ __align__(16) char smem[27648];

    const int bid = blockIdx.x;
    const int xcd = bid & 7;
    const int sub = bid >> 3;
    const int wid = (xcd < 2) ? (xcd * 111 + sub)
                              : (222 + (xcd - 2) * 110 + sub);
    const int img = wid / 9;                 // b*49 + uv
    const int xb  = wid - 9 * img;           // 0..8

    const int b   = img / 49;
    const int uvr = img - b * 49;
    const int u   = uvr / 7;
    const int v   = uvr - u * 7;
    const int cu  = 3 - (u == 0) - (u == 6);
    const int cv  = 3 - (v == 0) - (v == 6);
    const int nchunk = cu * cv * 3;          // 12, 18, or 27 (exact, no tail)

    const int lane = threadIdx.x & 63;
    const int wave = threadIdx.x >> 6;
    const int n    = lane & 15;              // col within 16-tile (B col, A m-row)
    const int quad = lane >> 4;              // j2 tap-row (B), k-group (A)

    const char* base0 = (const char*)ws16;

    // ---- stage Wp2 (27648 B) into LDS, lane-contiguous ----
    {
        const short8* src = (const short8*)(base0 + WP_OFF);
        short8* dst = (short8*)smem;
        for (int i = threadIdx.x; i < 1728; i += 256)
            dst[i] = src[i];
    }

    // Wave's two dtiles: dt = widx*2 + {0,1}; dt -> (row-pair rp, col base w0).
    const int widx = xb * 4 + wave;          // 0..35
    const int dt0  = widx * 2;
    const int rp0  = dt0 / 3,        w00 = (dt0 - 3 * rp0) * 16;
    const int dt1  = dt0 + 1;
    const int rp1  = dt1 / 3,        w01 = (dt1 - 3 * rp1) * 16;

    // B per-lane offsets: row' = rp*2 + quad, col' = w0 + n (+ i3*16 via tab).
    const int myoff0 = ((rp0 * 2 + quad) * 50 + w00 + n) * 16;
    const int myoff1 = ((rp1 * 2 + quad) * 50 + w01 + n) * 16;
    const int lane16 = lane * 16;

    // Hoist the 9 uniform slice-table entries into registers.
    const int* tblp = (const int*)(base0 + WT_OFF) + img * 9;
    int t[9];
#pragma unroll
    for (int k = 0; k < 9; ++k) t[k] = tblp[k];

    __syncthreads();                          // Wp2 staged

    f32x4 acc0 = (f32x4){0.f, 0.f, 0.f, 0.f};
    f32x4 acc1 = acc0;

#define CHUNK(c)                                                               \
    {                                                                          \
        int sl = (c) / 3, i3 = (c) % 3;                                        \
        int e   = t[sl];                                                       \
        int tab = (e & 0x3FFFFF) + i3 * 16;                                    \
        int wof = (((e >> 22) * 3 + i3) << 10);                                \
        short8 wf  = *(const short8*)(smem + wof + lane16);                    \
        const char* xb2 = base0 + tab;                                         \
        short8 xf0 = *(const short8*)(xb2 + myoff0);                           \
        short8 xf1 = *(const short8*)(xb2 + myoff1);                           \
        acc0 = __builtin_amdgcn_mfma_f32_16x16x32_bf16(wf, xf0, acc0, 0, 0, 0);\
        acc1 = __builtin_amdgcn_mfma_f32_16x16x32_bf16(wf, xf1, acc1, 0, 0, 0);\
    }

    // Exact sections for nchunk in {12, 18, 27}.
#pragma unroll
    for (int c = 0; c < 12; ++c) CHUNK(c);
    if (nchunk > 12) {
#pragma unroll
        for (int c = 12; c < 18; ++c) CHUNK(c);
        if (nchunk > 18) {
#pragma unroll
            for (int c = 18; c < 27; ++c) CHUNK(c);
        }
    }
#undef CHUNK

    // C/D: row m = quad*4 + r = o + 8d -> o = (quad&1)*4 + r, d = quad>>1.
    // col = n. Out row = rp*2 + d, out col = w0 + n.
    {
        const int d  = quad >> 1;
        const int oq = (quad & 1) * 4;
        const f32x4 bb = *(const f32x4*)(bias + oq);
        float* obase = out + ((size_t)(b * 8 + oq) * 49 + uvr) * 2304;
        float* ob0 = obase + (rp0 * 2 + d) * 48 + w00 + n;
        float* ob1 = obase + (rp1 * 2 + d) * 48 + w01 + n;
#pragma unroll
        for (int r = 0; r < 4; ++r) {
            ob0[(size_t)r * CSTRIDE] = acc0[r] + bb[r];
            ob1[(size_t)r * CSTRIDE] = acc1[r] + bb[r];
        }
    }
}

extern "C" void kernel_launch(void* const* d_in, const int* in_sizes, int n_in,
                              void* d_out, int out_size, void* d_ws, size_t ws_size,
                              hipStream_t stream) {
    const float* x    = (const float*)d_in[0];
    const float* conv = (const float*)d_in[1];
    const float* bias = (const float*)d_in[2];
    float* out = (float*)d_out;
    unsigned short* ws16 = (unsigned short*)d_ws;

    prep<<<dim3((92862 + 255) / 256), dim3(256), 0, stream>>>(x, conv, ws16);
    conv4d_mfma<<<dim3(882), dim3(256), 0, stream>>>(ws16, bias, out);
}